// Round 9
// baseline (446.087 us; speedup 1.0000x reference)
//
#include <hip/hip_runtime.h>
#include <math.h>

#define NN 30000
#define EE 480000
#define FIN 100
#define NCLS 47
#define NCOPY 16  // stat partial copies (contention vs reduce-cost tradeoff)

typedef unsigned short ushortt;
typedef __attribute__((ext_vector_type(8))) short bf16x8;
typedef __attribute__((ext_vector_type(8))) unsigned short us8;
typedef __attribute__((ext_vector_type(4))) float f32x4;
typedef __attribute__((ext_vector_type(2))) float f32x2;

// ---------------- static device workspace ----------------
// Xb/Fb/Wc* use a bank-conflict-killing swizzle: within each 64-col K-window,
// 8-ushort chunk index is XORed with (row & 7) (r15: conflicts 5.85M -> 682k).
// Logits g_als/g_ald are node-major [n*4+head].
__device__ unsigned char g_H8[(size_t)NN * 256];  // fp8 e4m3 h for the gathers (l2: ld=192)
__device__ ushortt g_Sb[(size_t)NN * 256];   // skip/pre-BN accumulator, bf16 (layers 0/1)
__device__ float   g_S2[(size_t)NN * 48];    // layer-2 skip, fp32 [N,47]
__device__ ushortt g_Fb[(size_t)NN * 256];   // post-BN features bf16, SWIZZLED
__device__ ushortt g_Xb[(size_t)NN * 128];   // x padded 100->128, bf16, SWIZZLED
__device__ ushortt g_Wc0[512 * 128];         // [W0 | SW0]^T bf16, SWIZZLED
__device__ ushortt g_Wc1[512 * 256];         // [W1 | SW1]^T, SWIZZLED
__device__ ushortt g_Wc2[235 * 256];         // [W2(188) | SW2(47)]^T, SWIZZLED
__device__ float g_als[NN * 4];
__device__ float g_ald[NN * 4];
__device__ int   g_rowptr[NN + 1];
__device__ int   g_counts[NN];               // degree counts; zeroed by scan_kernel each run
__device__ int   g_cur[NN];                  // scatter cursor; zeroed by scan_kernel each run
__device__ int   g_esrc[EE];                 // src node in CSR (dst-sorted) order
__device__ float g_stat[2 * NCOPY * 512];    // per-layer 16 partial copies of [sum|sumsq]

// ---------------- helpers ----------------
__device__ __forceinline__ float wsum(float v) {
#pragma unroll
  for (int o = 32; o > 0; o >>= 1) v += __shfl_xor(v, o, 64);
  return v;
}
__device__ __forceinline__ float lrelu(float x) { return x > 0.f ? x : 0.2f * x; }
__device__ __forceinline__ ushortt f2bf(float f) {
  unsigned int u = __float_as_uint(f);
  unsigned int r = u + 0x7FFF + ((u >> 16) & 1);
  return (ushortt)(r >> 16);
}
__device__ __forceinline__ float bf2f(ushortt u) {
  return __uint_as_float(((unsigned int)u) << 16);
}
__device__ __forceinline__ unsigned int pk4_fp8(float f0, float f1, float f2, float f3) {
  unsigned int r = 0;
  r = __builtin_amdgcn_cvt_pk_fp8_f32(f0, f1, r, false);
  r = __builtin_amdgcn_cvt_pk_fp8_f32(f2, f3, r, true);
  return r;
}
// swizzled column index: window=64 cols, chunk=8 cols, chunk ^= (row&7)
__device__ __forceinline__ int swz(int row, int k) {
  return (k & ~63) | ((((k >> 3) & 7) ^ (row & 7)) << 3) | (k & 7);
}
// async global->LDS, 16B per lane; lds dest = base + lane*16 (wave-uniform base)
__device__ __forceinline__ void glds16(const ushortt* gp, ushortt* lp) {
  __builtin_amdgcn_global_load_lds(
      (const __attribute__((address_space(1))) unsigned int*)gp,
      (__attribute__((address_space(3))) unsigned int*)lp, 16, 0, 0);
}

// ---------------- conversions + zero-init + degree count (ONE kernel, r24) ------------
// Disjoint index ranges; the count range only touches g_counts, which no other range
// touches (g_counts is zeroed by last run's scan_kernel / static init on run 1).
#define CW0 (512 * 128)
#define CW1 (512 * 256)
#define CW2 (235 * 256)
#define STATZ (2 * NCOPY * 512)
__global__ void conv_kernel(const float* __restrict__ w0, const float* __restrict__ sw0,
                            const float* __restrict__ w1, const float* __restrict__ sw1,
                            const float* __restrict__ w2, const float* __restrict__ sw2,
                            const float* __restrict__ x, const int* __restrict__ dst) {
  int i = blockIdx.x * blockDim.x + threadIdx.x;
  if (i < CW0) {
    int m = i >> 7, k = i & 127;
    float v = 0.f;
    if (k < FIN) v = (m < 256) ? w0[k * 256 + m] : sw0[k * 256 + (m - 256)];
    g_Wc0[(m << 7) | swz(m, k)] = f2bf(v);
    return;
  }
  i -= CW0;
  if (i < CW1) {
    int m = i >> 8, k = i & 255;
    float v = (m < 256) ? w1[k * 256 + m] : sw1[k * 256 + (m - 256)];
    g_Wc1[(m << 8) | swz(m, k)] = f2bf(v);
    return;
  }
  i -= CW1;
  if (i < CW2) {
    int m = i >> 8, k = i & 255;
    float v = (m < 188) ? w2[(size_t)k * 188 + m] : sw2[(size_t)k * 47 + (m - 188)];
    g_Wc2[(m << 8) | swz(m, k)] = f2bf(v);
    return;
  }
  i -= CW2;
  if (i < NN * 128) {
    int r = i >> 7, k = i & 127;
    g_Xb[(r << 7) | swz(r, k)] = (k < FIN) ? f2bf(x[r * FIN + k]) : 0;
    return;
  }
  i -= NN * 128;
  if (i < STATZ) {
    g_stat[i] = 0.f;
    return;
  }
  i -= STATZ;
  if (i < EE) atomicAdd(&g_counts[dst[i]], 1);
}

// ---------------- exclusive scan of 30000 degree counts, ONE 1024-thread block --------
// r25: TWO-PASS, no per-thread array. r8's cnt[30] was live across the scan ladder ->
// spilled to scratch (VGPR_Count=20!) -> 55us. Now pass 1 computes only the sum, the
// ladder scans 1024 sums, pass 2 RE-READS g_counts (L1/L2-hot, 120KB) and emits the
// running prefix. Per-thread live state = one scalar. Also zeroes g_counts (for next
// run's count) and g_cur (for this run's scatter).
__global__ __launch_bounds__(1024) void scan_kernel() {
  __shared__ int sh[1024];
  int t = threadIdx.x;
  int base = t * 30;
  int sum = 0;
#pragma unroll
  for (int k = 0; k < 30; k++) {
    int i = base + k;
    sum += (i < NN) ? g_counts[i] : 0;
  }
  sh[t] = sum;
  __syncthreads();
  for (int off = 1; off < 1024; off <<= 1) {
    int xv = (t >= off) ? sh[t - off] : 0;
    __syncthreads();
    sh[t] += xv;
    __syncthreads();
  }
  int run = sh[t] - sum;  // exclusive prefix of this thread's chunk
#pragma unroll
  for (int k = 0; k < 30; k++) {
    int i = base + k;
    if (i < NN) {
      int v = g_counts[i];  // re-read, cache-hot
      g_rowptr[i] = run;
      run += v;
      g_counts[i] = 0;
      g_cur[i] = 0;
    }
  }
  if (t == 0) g_rowptr[NN] = EE;
}
__global__ void scatter_kernel(const int* __restrict__ dst, const int* __restrict__ src) {
  int e = blockIdx.x * blockDim.x + threadIdx.x;
  if (e < EE) {
    int d = dst[e];
    int pos = g_rowptr[d] + atomicAdd(&g_cur[d], 1);
    g_esrc[pos] = src[e];
  }
}

// ---------------- MFMA GEMM, 64x128 tile, BK=64, global_load_lds, swizzled LDS ----------
// r19 structure (best of 4 tried: r18 dbuf, r20 barrier-free, r21 128x128, r22 coop all
// regressed). LDS 24KB: staging 12288 ushorts; epilogue reuses as 32x132 fp32, 2 passes.
__global__ __launch_bounds__(256) void mfma_gemm(
    const ushortt* __restrict__ A, const ushortt* __restrict__ Wt,
    unsigned char* __restrict__ out8, ushortt* __restrict__ out2b,
    float* __restrict__ out2f,
    int nrows, int Kp, int M, int S, int ld8, int ld2,
    const float* __restrict__ bias2, int pad47,
    const float* __restrict__ a_s, const float* __restrict__ a_d,
    float* __restrict__ alsp, float* __restrict__ aldp) {
  __shared__ __align__(16) ushortt smem[12288];
  ushortt* As = smem;            // 64 x 64
  ushortt* Ws = smem + 64 * 64;  // 128 x 64
  float* Ls = (float*)smem;      // 32 x (stride 132) f32
  int t = threadIdx.x;
  int wave = t >> 6, lane = t & 63;
  int row0 = blockIdx.y * 64, col0 = blockIdx.x * 128;
  int wr = wave >> 1, wc = wave & 1;  // 2 row-halves x 2 col-halves
  int m16 = lane & 15, q = lane >> 4;
  int rin8 = lane >> 3;            // 0..7 row within 8-row staging group
  int koff = (lane & 7) * 8;       // k offset in ushorts within 64-k row

  f32x4 acc[2][4];
#pragma unroll
  for (int i = 0; i < 2; i++)
#pragma unroll
    for (int j = 0; j < 4; j++) acc[i][j] = (f32x4){0.f, 0.f, 0.f, 0.f};

  for (int k0 = 0; k0 < Kp; k0 += 64) {
#pragma unroll
    for (int r = 0; r < 2; r++) {
      int lrow = wave * 16 + r * 8;
      int ga = min(row0 + lrow + rin8, nrows - 1);
      glds16(A + (size_t)ga * Kp + k0 + koff, &As[lrow * 64]);
    }
#pragma unroll
    for (int r = 0; r < 4; r++) {
      int lrow = wave * 32 + r * 8;
      int gw = min(col0 + lrow + rin8, M - 1);
      glds16(Wt + (size_t)gw * Kp + k0 + koff, &Ws[lrow * 64]);
    }
    __syncthreads();
#pragma unroll
    for (int c = 0; c < 2; c++) {
      bf16x8 af[2], bf[4];
#pragma unroll
      for (int i = 0; i < 2; i++) {
        int row = wr * 32 + i * 16 + m16;
        int ch = (c * 4 + q) ^ (row & 7);  // de-swizzle: conflict-free across m16 rows
        af[i] = *(const bf16x8*)(&As[row * 64 + ch * 8]);
      }
#pragma unroll
      for (int i = 0; i < 4; i++) {
        int row = wc * 64 + i * 16 + m16;
        int ch = (c * 4 + q) ^ (row & 7);
        bf[i] = *(const bf16x8*)(&Ws[row * 64 + ch * 8]);
      }
#pragma unroll
      for (int rt = 0; rt < 2; rt++)
#pragma unroll
        for (int ct = 0; ct < 4; ct++)
          acc[rt][ct] = __builtin_amdgcn_mfma_f32_16x16x32_bf16(af[rt], bf[ct], acc[rt][ct], 0, 0, 0);
    }
    __syncthreads();
  }

  // ---- two-pass epilogue: 32 rows/pass through the 16.9KB buffer ----
  bool all1 = (!pad47) && (col0 + 128 <= S);
  bool all2 = (col0 >= S);
  int row8 = t >> 3, seg = t & 7;  // row8 0..31, seg 0..7
#pragma unroll
  for (int p = 0; p < 2; p++) {
    __syncthreads();  // pass 0: staging reads done; pass 1: pass-0 LDS reads done
    if (wr == p) {
#pragma unroll
      for (int rt = 0; rt < 2; rt++) {
#pragma unroll
        for (int ctt = 0; ctt < 4; ctt++) {
#pragma unroll
          for (int reg = 0; reg < 4; reg++) {
            int rloc = rt * 16 + q * 4 + reg;  // 0..31
            Ls[rloc * 132 + wc * 64 + ctt * 16 + m16] = acc[rt][ctt][reg];
          }
        }
      }
    }
    __syncthreads();
    int grow = row0 + p * 32 + row8;
    if (grow < nrows) {
      const float* lrow = Ls + row8 * 132 + seg * 16;
      int cbase = col0 + seg * 16;
      if (all1) {
        unsigned int q8[4];
#pragma unroll
        for (int kk = 0; kk < 4; kk++)
          q8[kk] = pk4_fp8(lrow[kk * 4], lrow[kk * 4 + 1], lrow[kk * 4 + 2], lrow[kk * 4 + 3]);
        uint4 v8 = {q8[0], q8[1], q8[2], q8[3]};
        *(uint4*)(out8 + (size_t)grow * ld8 + cbase) = v8;
        // fused attention-logit partials: this thread covers 16 ch of head cbase>>6
        float s_p = 0.f, d_p = 0.f;
#pragma unroll
        for (int kk = 0; kk < 16; kk++) {
          s_p += lrow[kk] * a_s[cbase + kk];
          d_p += lrow[kk] * a_d[cbase + kk];
        }
        s_p += __shfl_xor(s_p, 1, 64); s_p += __shfl_xor(s_p, 2, 64);
        d_p += __shfl_xor(d_p, 1, 64); d_p += __shfl_xor(d_p, 2, 64);
        if ((seg & 3) == 0) {
          int head = cbase >> 6;
          alsp[grow * 4 + head] = s_p;
          aldp[grow * 4 + head] = d_p;
        }
      } else if (all2) {
        const float* brow = bias2 + (cbase - S);
        // bf16 skip store (layers 0/1): 16 cols -> 8 packed uints -> 2 uint4 stores
        ushortt* orow = out2b + (size_t)grow * ld2 + (cbase - S);
        unsigned int pk[8];
#pragma unroll
        for (int kk = 0; kk < 8; kk++) {
          unsigned int lo = f2bf(lrow[kk * 2] + brow[kk * 2]);
          unsigned int hi = f2bf(lrow[kk * 2 + 1] + brow[kk * 2 + 1]);
          pk[kk] = lo | (hi << 16);
        }
        uint4 v0 = {pk[0], pk[1], pk[2], pk[3]};
        uint4 v1 = {pk[4], pk[5], pk[6], pk[7]};
        *(uint4*)(orow) = v0;
        *(uint4*)(orow + 8) = v1;
      } else {
        // layer-2 mixed tile: scalar h stores (fp8, padded 47->48) + fp32 skip cols +
        // atomic logit partials (head = c/47, at most 2 heads per thread)
        float pa0 = 0.f, pa1 = 0.f, pd0 = 0.f, pd1 = 0.f;
        int h0 = cbase / 47;
        for (int kk = 0; kk < 16; kk++) {
          int c = cbase + kk;
          if (c >= M) break;
          float v = lrow[kk];
          if (c < S) {
            int hd = c / 47, ch = c - hd * 47;
            int c1 = hd * 48 + ch;
            out8[(size_t)grow * ld8 + c1] =
                (unsigned char)(pk4_fp8(v, 0.f, 0.f, 0.f) & 0xFF);
            if (ch == 46) out8[(size_t)grow * ld8 + c1 + 1] = 0;
            float sw = a_s[hd * 47 + ch], dw = a_d[hd * 47 + ch];
            if (hd == h0) { pa0 += v * sw; pd0 += v * dw; }
            else { pa1 += v * sw; pd1 += v * dw; }
          } else {
            out2f[(size_t)grow * ld2 + (c - S)] = v + bias2[c - S];
          }
        }
        if (pad47 && cbase < S) {
          if (pa0 != 0.f || pd0 != 0.f) {
            atomicAdd(&alsp[grow * 4 + h0], pa0);
            atomicAdd(&aldp[grow * 4 + h0], pd0);
          }
          if ((pa1 != 0.f || pd1 != 0.f) && h0 + 1 < 4) {
            atomicAdd(&alsp[grow * 4 + h0 + 1], pa1);
            atomicAdd(&aldp[grow * 4 + h0 + 1], pd1);
          }
        }
      }
    }
  }
}

// ---------------- fused softmax + aggregate + skip-add + BN-STATS (r24) ---------------
// 4 nodes per block (one per wave, r23). After writing Sb, the block reduces its
// 4 nodes' column sums/sumsq in LDS and atomically adds them into stat copy
// (blockIdx.x & 15) — replaces the separate bn_stats kernel. Stats use the bf16-rounded
// Sb values (identical numerics to the old bn_stats read-back).
__global__ __launch_bounds__(256) void attn_kernel(const unsigned char* __restrict__ H8,
                                                   const float* __restrict__ bias,
                                                   ushortt* __restrict__ Sb,
                                                   float* __restrict__ statp) {
  __shared__ __align__(16) float p_sh[4 * 256];
  __shared__ int s_sh[4 * 64];
  __shared__ float rs_[4 * 256];
  __shared__ float rq_[4 * 256];
  int w = threadIdx.x >> 6, lane = threadIdx.x & 63;
  int n = blockIdx.x * 4 + w;
  float* pw = p_sh + w * 256;
  int* sw_ = s_sh + w * 64;
  int rs = g_rowptr[n], deg = g_rowptr[n + 1] - rs;
  float4 ald = *(const float4*)(g_ald + n * 4);
  int q = lane >> 4;
  float den0 = 0, den1 = 0, den2 = 0, den3 = 0;
  float a0 = 0, a1 = 0, a2 = 0, a3 = 0;
  for (int base = 0; base < deg; base += 64) {
    int j = base + lane;
    float p0 = 0, p1 = 0, p2 = 0, p3 = 0;
    int s = 0;
    if (j < deg) {
      s = g_esrc[rs + j];
      float4 av = *(const float4*)(g_als + s * 4);
      p0 = __expf(lrelu(av.x + ald.x)); den0 += p0;
      p1 = __expf(lrelu(av.y + ald.y)); den1 += p1;
      p2 = __expf(lrelu(av.z + ald.z)); den2 += p2;
      p3 = __expf(lrelu(av.w + ald.w)); den3 += p3;
    }
    pw[lane * 4 + 0] = p0; pw[lane * 4 + 1] = p1;
    pw[lane * 4 + 2] = p2; pw[lane * 4 + 3] = p3;
    sw_[lane] = s;
    int cnt = min(64, deg - base);
    for (int jj = 0; jj < cnt; jj++) {
      int ss = sw_[jj];
      float p = pw[jj * 4 + q];
      unsigned int hv = *(const unsigned int*)(H8 + (size_t)ss * 256 + 4 * lane);
      f32x2 lo = __builtin_amdgcn_cvt_pk_f32_fp8(hv, false);
      f32x2 hi = __builtin_amdgcn_cvt_pk_f32_fp8(hv, true);
      a0 += p * lo.x;
      a1 += p * lo.y;
      a2 += p * hi.x;
      a3 += p * hi.y;
    }
  }
  den0 = wsum(den0); den1 = wsum(den1); den2 = wsum(den2); den3 = wsum(den3);
  float denq = (q == 0) ? den0 : (q == 1) ? den1 : (q == 2) ? den2 : den3;
  float inv = 1.f / (denq + 1e-16f);
  size_t o = (size_t)n * 256 + 4 * lane;
  ushort4 sv = *(const ushort4*)(Sb + o);
  float4 bv = *(const float4*)(bias + 4 * lane);
  ushort4 ov;
  ov.x = f2bf(a0 * inv + bv.x + bf2f(sv.x));
  ov.y = f2bf(a1 * inv + bv.y + bf2f(sv.y));
  ov.z = f2bf(a2 * inv + bv.z + bf2f(sv.z));
  ov.w = f2bf(a3 * inv + bv.w + bf2f(sv.w));
  *(ushort4*)(Sb + o) = ov;
  // ---- fused BN partial stats: block-level column sums over the 4 nodes ----
  float v0 = bf2f(ov.x), v1 = bf2f(ov.y), v2 = bf2f(ov.z), v3 = bf2f(ov.w);
  int cb = w * 256 + 4 * lane;
  rs_[cb + 0] = v0; rs_[cb + 1] = v1; rs_[cb + 2] = v2; rs_[cb + 3] = v3;
  rq_[cb + 0] = v0 * v0; rq_[cb + 1] = v1 * v1; rq_[cb + 2] = v2 * v2; rq_[cb + 3] = v3 * v3;
  __syncthreads();
  int c = threadIdx.x;  // 0..255 = column
  float s = rs_[c] + rs_[256 + c] + rs_[512 + c] + rs_[768 + c];
  float qq = rq_[c] + rq_[256 + c] + rq_[512 + c] + rq_[768 + c];
  int copy = blockIdx.x & (NCOPY - 1);
  atomicAdd(&statp[copy * 512 + c], s);
  atomicAdd(&statp[copy * 512 + 256 + c], qq);
}

// ---------------- layer-2: softmax + aggregate (fp8, ld=192) + mean + skip + log_softmax -
// r23: 4 nodes per block, one per wave, per-wave LDS slices, no barriers.
__global__ __launch_bounds__(256) void attn2_kernel(const unsigned char* __restrict__ H8,
                                                    const float* __restrict__ bias,
                                                    const float* __restrict__ S2,
                                                    float* __restrict__ out) {
  __shared__ __align__(16) float p_sh[4 * 256];
  __shared__ int s_sh[4 * 64];
  __shared__ float xh[4][4][48];
  int w = threadIdx.x >> 6, lane = threadIdx.x & 63;
  int n = blockIdx.x * 4 + w;
  float* pw = p_sh + w * 256;
  int* sw_ = s_sh + w * 64;
  int rs = g_rowptr[n], deg = g_rowptr[n + 1] - rs;
  float4 ald = *(const float4*)(g_ald + n * 4);
  int head = lane / 12;  // valid for lane<48
  float den0 = 0, den1 = 0, den2 = 0, den3 = 0;
  float a0 = 0, a1 = 0, a2 = 0, a3 = 0;
  for (int base = 0; base < deg; base += 64) {
    int j = base + lane;
    float p0 = 0, p1 = 0, p2 = 0, p3 = 0;
    int s = 0;
    if (j < deg) {
      s = g_esrc[rs + j];
      float4 av = *(const float4*)(g_als + s * 4);
      p0 = __expf(lrelu(av.x + ald.x)); den0 += p0;
      p1 = __expf(lrelu(av.y + ald.y)); den1 += p1;
      p2 = __expf(lrelu(av.z + ald.z)); den2 += p2;
      p3 = __expf(lrelu(av.w + ald.w)); den3 += p3;
    }
    pw[lane * 4 + 0] = p0; pw[lane * 4 + 1] = p1;
    pw[lane * 4 + 2] = p2; pw[lane * 4 + 3] = p3;
    sw_[lane] = s;
    int cnt = min(64, deg - base);
    if (lane < 48) {
      for (int jj = 0; jj < cnt; jj++) {
        int ss = sw_[jj];
        float p = pw[jj * 4 + head];
        unsigned int hv = *(const unsigned int*)(H8 + (size_t)ss * 192 + lane * 4);
        f32x2 lo = __builtin_amdgcn_cvt_pk_f32_fp8(hv, false);
        f32x2 hi = __builtin_amdgcn_cvt_pk_f32_fp8(hv, true);
        a0 += p * lo.x;
        a1 += p * lo.y;
        a2 += p * hi.x;
        a3 += p * hi.y;
      }
    }
  }
  den0 = wsum(den0); den1 = wsum(den1); den2 = wsum(den2); den3 = wsum(den3);
  if (lane < 48) {
    float dh = (head == 0) ? den0 : (head == 1) ? den1 : (head == 2) ? den2 : den3;
    float inv = 1.f / (dh + 1e-16f);
    int chin = (lane % 12) * 4;
    xh[w][head][chin + 0] = a0 * inv;
    xh[w][head][chin + 1] = a1 * inv;
    xh[w][head][chin + 2] = a2 * inv;
    xh[w][head][chin + 3] = a3 * inv;
  }
  float v = 0.f;
  if (lane < NCLS)
    v = 0.25f * (xh[w][0][lane] + xh[w][1][lane] + xh[w][2][lane] + xh[w][3][lane]) +
        bias[lane] + S2[(size_t)n * NCLS + lane];
  // fused log_softmax over the 47 classes
  float mv = (lane < NCLS) ? v : -INFINITY;
#pragma unroll
  for (int o = 32; o > 0; o >>= 1) mv = fmaxf(mv, __shfl_xor(mv, o, 64));
  float ex = (lane < NCLS) ? __expf(v - mv) : 0.f;
  float s = wsum(ex);
  if (lane < NCLS) out[(size_t)n * NCLS + lane] = v - mv - logf(s);
}

// ---------------- BatchNorm normalize + ELU (r24: stats reduced in-kernel) -------------
// Reduces the NCOPY stat partials per column (32 loads/thread), folds gamma/beta, then
// processes rows with ushort8 (16B) loads/stores (G13). 480 blocks x 256 threads;
// thread t handles 8-col chunk (t&31) of rows r0 + (t>>5) + 8k. Fb store is swizzled
// (8-col chunks move as units under swz, so 16B stores stay contiguous).
__global__ __launch_bounds__(256) void bn_norm_kernel(const ushortt* __restrict__ Sb,
                                                      const float* __restrict__ gamma,
                                                      const float* __restrict__ beta,
                                                      const float* __restrict__ statp,
                                                      float* __restrict__ zs,
                                                      float* __restrict__ zd) {
  __shared__ float sc_sh[256], off_sh[256];
  int t = threadIdx.x;
  float s = 0.f, qq = 0.f;
#pragma unroll
  for (int k = 0; k < NCOPY; k++) {
    s += statp[k * 512 + t];
    qq += statp[k * 512 + 256 + t];
  }
  float mu = s * (1.f / NN);
  float var = qq * (1.f / NN) - mu * mu;
  float rg = rsqrtf(var + 1e-5f) * gamma[t];
  sc_sh[t] = rg;
  off_sh[t] = beta[t] - mu * rg;
  __syncthreads();
  if (zs) {
    for (int i = blockIdx.x * 256 + t; i < NN * 4; i += gridDim.x * 256) {
      zs[i] = 0.f;
      zd[i] = 0.f;
    }
  }
  int rows = (NN + gridDim.x - 1) / gridDim.x;
  int r0 = blockIdx.x * rows, r1 = min(r0 + rows, NN);
  int chunk = t & 31;  // 8-col chunk
  int ro = t >> 5;     // 0..7
  float scv[8], ofv[8];
#pragma unroll
  for (int k = 0; k < 8; k++) {
    scv[k] = sc_sh[chunk * 8 + k];
    ofv[k] = off_sh[chunk * 8 + k];
  }
  for (int r = r0 + ro; r < r1; r += 8) {
    us8 xv = *(const us8*)(Sb + (size_t)r * 256 + chunk * 8);
    us8 yv;
#pragma unroll
    for (int k = 0; k < 8; k++) {
      float v = bf2f((ushortt)xv[k]) * scv[k] + ofv[k];
      v = v > 0.f ? v : (__expf(v) - 1.f);  // ELU
      yv[k] = f2bf(v);
    }
    int c8 = (chunk & 24) | ((chunk & 7) ^ (r & 7));  // swizzled chunk index
    *(us8*)(g_Fb + ((size_t)r << 8) + c8 * 8) = yv;
  }
}

// ---------------- launch ----------------
extern "C" void kernel_launch(void* const* d_in, const int* in_sizes, int n_in,
                              void* d_out, int out_size, void* d_ws, size_t ws_size,
                              hipStream_t stream) {
  const float* x = (const float*)d_in[0];
  const int* ei = (const int*)d_in[1];
  const int* src = ei;
  const int* dst = ei + EE;
  const float* w0 = (const float*)d_in[2];
  const float* as0 = (const float*)d_in[3];
  const float* ad0 = (const float*)d_in[4];
  const float* b0 = (const float*)d_in[5];
  const float* sw0 = (const float*)d_in[6];
  const float* sb0 = (const float*)d_in[7];
  const float* gm0 = (const float*)d_in[8];
  const float* be0 = (const float*)d_in[9];
  const float* w1 = (const float*)d_in[10];
  const float* as1 = (const float*)d_in[11];
  const float* ad1 = (const float*)d_in[12];
  const float* b1 = (const float*)d_in[13];
  const float* sw1 = (const float*)d_in[14];
  const float* sb1 = (const float*)d_in[15];
  const float* gm1 = (const float*)d_in[16];
  const float* be1 = (const float*)d_in[17];
  const float* w2 = (const float*)d_in[18];
  const float* as2 = (const float*)d_in[19];
  const float* ad2 = (const float*)d_in[20];
  const float* b2 = (const float*)d_in[21];
  const float* sw2 = (const float*)d_in[22];
  const float* sb2 = (const float*)d_in[23];
  float* out = (float*)d_out;

  ushortt *Sb, *Fb, *Xb, *Wc0, *Wc1, *Wc2;
  unsigned char* H8;
  float *S2, *als, *ald, *stat;
  hipGetSymbolAddress((void**)&H8, HIP_SYMBOL(g_H8));
  hipGetSymbolAddress((void**)&Sb, HIP_SYMBOL(g_Sb));
  hipGetSymbolAddress((void**)&S2, HIP_SYMBOL(g_S2));
  hipGetSymbolAddress((void**)&Fb, HIP_SYMBOL(g_Fb));
  hipGetSymbolAddress((void**)&Xb, HIP_SYMBOL(g_Xb));
  hipGetSymbolAddress((void**)&Wc0, HIP_SYMBOL(g_Wc0));
  hipGetSymbolAddress((void**)&Wc1, HIP_SYMBOL(g_Wc1));
  hipGetSymbolAddress((void**)&Wc2, HIP_SYMBOL(g_Wc2));
  hipGetSymbolAddress((void**)&als, HIP_SYMBOL(g_als));
  hipGetSymbolAddress((void**)&ald, HIP_SYMBOL(g_ald));
  hipGetSymbolAddress((void**)&stat, HIP_SYMBOL(g_stat));

  // conversions + zero-init + degree count (one kernel)
  const int convN = CW0 + CW1 + CW2 + NN * 128 + STATZ + EE;
  conv_kernel<<<(convN + 255) / 256, 256, 0, stream>>>(w0, sw0, w1, sw1, w2, sw2, x, dst);

  // CSR: single-block two-pass scan, then scatter
  scan_kernel<<<1, 1024, 0, stream>>>();
  scatter_kernel<<<(EE + 255) / 256, 256, 0, stream>>>(dst, src);

  const int gy = (NN + 63) / 64;  // 469
  const int ga = NN / 4;          // 7500 (exact)

  // ---- layer 0 ----
  mfma_gemm<<<dim3(4, gy), 256, 0, stream>>>(Xb, Wc0, H8, Sb, nullptr, NN, 128, 512, 256,
                                             256, 256, sb0, 0, as0, ad0, als, ald);
  attn_kernel<<<ga, 256, 0, stream>>>(H8, b0, Sb, stat);
  bn_norm_kernel<<<480, 256, 0, stream>>>(Sb, gm0, be0, stat, nullptr, nullptr);

  // ---- layer 1 ----
  mfma_gemm<<<dim3(4, gy), 256, 0, stream>>>(Fb, Wc1, H8, Sb, nullptr, NN, 256, 512, 256,
                                             256, 256, sb1, 0, as1, ad1, als, ald);
  attn_kernel<<<ga, 256, 0, stream>>>(H8, b1, Sb, stat + NCOPY * 512);
  bn_norm_kernel<<<480, 256, 0, stream>>>(Sb, gm1, be1, stat + NCOPY * 512, als, ald);

  // ---- layer 2 (h fp8 padded: ld=192, 48/head; skip -> S2[N,47] fp32; logits atomic) ----
  mfma_gemm<<<dim3(2, gy), 256, 0, stream>>>(Fb, Wc2, H8, nullptr, S2, NN, 256, 235, 188,
                                             192, 47, sb2, 1, as2, ad2, als, ald);
  attn2_kernel<<<ga, 256, 0, stream>>>(H8, b2, S2, out);
}

// Round 11
// 385.344 us; speedup vs baseline: 1.1576x; 1.1576x over previous
//
#include <hip/hip_runtime.h>
#include <math.h>

#define NN 30000
#define EE 480000
#define FIN 100
#define NCLS 47
#define NCOPY 16   // stat partial copies (contention vs reduce-cost tradeoff)
#define SCAN_B 118 // ceil(30000/256)

typedef unsigned short ushortt;
typedef __attribute__((ext_vector_type(8))) short bf16x8;
typedef __attribute__((ext_vector_type(8))) unsigned short us8;
typedef __attribute__((ext_vector_type(4))) float f32x4;
typedef __attribute__((ext_vector_type(2))) float f32x2;

// ---------------- static device workspace ----------------
// Xb/Fb/Wc* use a bank-conflict-killing swizzle: within each 64-col K-window,
// 8-ushort chunk index is XORed with (row & 7) (r15: conflicts 5.85M -> 682k).
// Logits g_als/g_ald are node-major [n*4+head].
__device__ unsigned char g_H8[(size_t)NN * 256];  // fp8 e4m3 h for the gathers (l2: ld=192)
__device__ ushortt g_Sb[(size_t)NN * 256];   // skip/pre-BN accumulator, bf16 (layers 0/1)
__device__ float   g_S2[(size_t)NN * 48];    // layer-2 skip, fp32 [N,47]
__device__ ushortt g_Fb[(size_t)NN * 256];   // post-BN features bf16, SWIZZLED
__device__ ushortt g_Xb[(size_t)NN * 128];   // x padded 100->128, bf16, SWIZZLED
__device__ ushortt g_Wc0[512 * 128];         // [W0 | SW0]^T bf16, SWIZZLED
__device__ ushortt g_Wc1[512 * 256];         // [W1 | SW1]^T, SWIZZLED
__device__ ushortt g_Wc2[235 * 256];         // [W2(188) | SW2(47)]^T, SWIZZLED
__device__ float g_als[NN * 4];
__device__ float g_ald[NN * 4];
__device__ int   g_rowptr[NN + 1];
__device__ int   g_counts[NN];               // degree counts; zeroed by scan_a each run
__device__ int   g_cur[NN];                  // scatter cursor; zeroed by scan_a each run
__device__ int   g_bsum[128];                // per-chunk totals
__device__ int   g_esrc[EE];                 // src node in CSR (dst-sorted) order
__device__ float g_stat[2 * NCOPY * 512];    // per-layer 16 partial copies of [sum|sumsq]

// ---------------- helpers ----------------
__device__ __forceinline__ float wsum(float v) {
#pragma unroll
  for (int o = 32; o > 0; o >>= 1) v += __shfl_xor(v, o, 64);
  return v;
}
__device__ __forceinline__ float lrelu(float x) { return x > 0.f ? x : 0.2f * x; }
__device__ __forceinline__ ushortt f2bf(float f) {
  unsigned int u = __float_as_uint(f);
  unsigned int r = u + 0x7FFF + ((u >> 16) & 1);
  return (ushortt)(r >> 16);
}
__device__ __forceinline__ float bf2f(ushortt u) {
  return __uint_as_float(((unsigned int)u) << 16);
}
__device__ __forceinline__ unsigned int pk4_fp8(float f0, float f1, float f2, float f3) {
  unsigned int r = 0;
  r = __builtin_amdgcn_cvt_pk_fp8_f32(f0, f1, r, false);
  r = __builtin_amdgcn_cvt_pk_fp8_f32(f2, f3, r, true);
  return r;
}
// swizzled column index: window=64 cols, chunk=8 cols, chunk ^= (row&7)
__device__ __forceinline__ int swz(int row, int k) {
  return (k & ~63) | ((((k >> 3) & 7) ^ (row & 7)) << 3) | (k & 7);
}
// async global->LDS, 16B per lane; lds dest = base + lane*16 (wave-uniform base)
__device__ __forceinline__ void glds16(const ushortt* gp, ushortt* lp) {
  __builtin_amdgcn_global_load_lds(
      (const __attribute__((address_space(1))) unsigned int*)gp,
      (__attribute__((address_space(3))) unsigned int*)lp, 16, 0, 0);
}

// ---------------- conversions + zero-init + degree count (ONE kernel, r24) ------------
// Disjoint index ranges; the count range only touches g_counts, which no other range
// touches (g_counts is zeroed by last run's scan_a / static init on run 1).
#define CW0 (512 * 128)
#define CW1 (512 * 256)
#define CW2 (235 * 256)
#define STATZ (2 * NCOPY * 512)
__global__ void conv_kernel(const float* __restrict__ w0, const float* __restrict__ sw0,
                            const float* __restrict__ w1, const float* __restrict__ sw1,
                            const float* __restrict__ w2, const float* __restrict__ sw2,
                            const float* __restrict__ x, const int* __restrict__ dst) {
  int i = blockIdx.x * blockDim.x + threadIdx.x;
  if (i < CW0) {
    int m = i >> 7, k = i & 127;
    float v = 0.f;
    if (k < FIN) v = (m < 256) ? w0[k * 256 + m] : sw0[k * 256 + (m - 256)];
    g_Wc0[(m << 7) | swz(m, k)] = f2bf(v);
    return;
  }
  i -= CW0;
  if (i < CW1) {
    int m = i >> 8, k = i & 255;
    float v = (m < 256) ? w1[k * 256 + m] : sw1[k * 256 + (m - 256)];
    g_Wc1[(m << 8) | swz(m, k)] = f2bf(v);
    return;
  }
  i -= CW1;
  if (i < CW2) {
    int m = i >> 8, k = i & 255;
    float v = (m < 188) ? w2[(size_t)k * 188 + m] : sw2[(size_t)k * 47 + (m - 188)];
    g_Wc2[(m << 8) | swz(m, k)] = f2bf(v);
    return;
  }
  i -= CW2;
  if (i < NN * 128) {
    int r = i >> 7, k = i & 127;
    g_Xb[(r << 7) | swz(r, k)] = (k < FIN) ? f2bf(x[r * FIN + k]) : 0;
    return;
  }
  i -= NN * 128;
  if (i < STATZ) {
    g_stat[i] = 0.f;
    return;
  }
  i -= STATZ;
  if (i < EE) atomicAdd(&g_counts[dst[i]], 1);
}

// ---------------- CSR scan, TWO multi-block dispatches (r26) --------------------------
// r25's single-1024-thread-block scan ran on ONE CU with stride-120B uncoalesced reads
// (74us, Occupancy 0.13%). Back to the proven multi-block shape, compressed to 2
// kernels: scan_a does per-chunk LDS scans (coalesced, 118 blocks in parallel) and
// chunk totals; scan_b block b reduces bsum[0..b) (L2-hot, <=118 ints) and adds the
// offset. scan_a also zeroes g_counts (next run) and g_cur (this run's scatter).
__global__ __launch_bounds__(256) void scan_a() {
  __shared__ int sh[256];
  int t = threadIdx.x;
  int i = blockIdx.x * 256 + t;
  int v = (i < NN) ? g_counts[i] : 0;
  sh[t] = v;
  __syncthreads();
  for (int off = 1; off < 256; off <<= 1) {
    int xv = (t >= off) ? sh[t - off] : 0;
    __syncthreads();
    sh[t] += xv;
    __syncthreads();
  }
  if (i < NN) {
    g_rowptr[i] = sh[t] - v;  // local exclusive prefix
    g_counts[i] = 0;
    g_cur[i] = 0;
  }
  if (t == 255) g_bsum[blockIdx.x] = sh[255];
}
__global__ __launch_bounds__(256) void scan_b() {
  __shared__ int sh[4];
  int t = threadIdx.x;
  int b = blockIdx.x;
  int v = (t < b) ? g_bsum[t] : 0;  // b<=117 < 128 entries valid
  float fv = wsum((float)v);        // totals <= 480000, exact in f32
  if ((t & 63) == 0) sh[t >> 6] = (int)fv;
  __syncthreads();
  int off = sh[0] + sh[1] + sh[2] + sh[3];
  int i = b * 256 + t;
  if (i < NN) g_rowptr[i] += off;
  if (i == NN - 1) g_rowptr[NN] = EE;
}
__global__ void scatter_kernel(const int* __restrict__ dst, const int* __restrict__ src) {
  int e = blockIdx.x * blockDim.x + threadIdx.x;
  if (e < EE) {
    int d = dst[e];
    int pos = g_rowptr[d] + atomicAdd(&g_cur[d], 1);
    g_esrc[pos] = src[e];
  }
}

// ---------------- MFMA GEMM, 64x128 tile, BK=64, global_load_lds, swizzled LDS ----------
// r19 structure (best of 4 tried: r18 dbuf, r20 barrier-free, r21 128x128, r22 coop all
// regressed). LDS 24KB: staging 12288 ushorts; epilogue reuses as 32x132 fp32, 2 passes.
__global__ __launch_bounds__(256) void mfma_gemm(
    const ushortt* __restrict__ A, const ushortt* __restrict__ Wt,
    unsigned char* __restrict__ out8, ushortt* __restrict__ out2b,
    float* __restrict__ out2f,
    int nrows, int Kp, int M, int S, int ld8, int ld2,
    const float* __restrict__ bias2, int pad47,
    const float* __restrict__ a_s, const float* __restrict__ a_d,
    float* __restrict__ alsp, float* __restrict__ aldp) {
  __shared__ __align__(16) ushortt smem[12288];
  ushortt* As = smem;            // 64 x 64
  ushortt* Ws = smem + 64 * 64;  // 128 x 64
  float* Ls = (float*)smem;      // 32 x (stride 132) f32
  int t = threadIdx.x;
  int wave = t >> 6, lane = t & 63;
  int row0 = blockIdx.y * 64, col0 = blockIdx.x * 128;
  int wr = wave >> 1, wc = wave & 1;  // 2 row-halves x 2 col-halves
  int m16 = lane & 15, q = lane >> 4;
  int rin8 = lane >> 3;            // 0..7 row within 8-row staging group
  int koff = (lane & 7) * 8;       // k offset in ushorts within 64-k row

  f32x4 acc[2][4];
#pragma unroll
  for (int i = 0; i < 2; i++)
#pragma unroll
    for (int j = 0; j < 4; j++) acc[i][j] = (f32x4){0.f, 0.f, 0.f, 0.f};

  for (int k0 = 0; k0 < Kp; k0 += 64) {
#pragma unroll
    for (int r = 0; r < 2; r++) {
      int lrow = wave * 16 + r * 8;
      int ga = min(row0 + lrow + rin8, nrows - 1);
      glds16(A + (size_t)ga * Kp + k0 + koff, &As[lrow * 64]);
    }
#pragma unroll
    for (int r = 0; r < 4; r++) {
      int lrow = wave * 32 + r * 8;
      int gw = min(col0 + lrow + rin8, M - 1);
      glds16(Wt + (size_t)gw * Kp + k0 + koff, &Ws[lrow * 64]);
    }
    __syncthreads();
#pragma unroll
    for (int c = 0; c < 2; c++) {
      bf16x8 af[2], bf[4];
#pragma unroll
      for (int i = 0; i < 2; i++) {
        int row = wr * 32 + i * 16 + m16;
        int ch = (c * 4 + q) ^ (row & 7);  // de-swizzle: conflict-free across m16 rows
        af[i] = *(const bf16x8*)(&As[row * 64 + ch * 8]);
      }
#pragma unroll
      for (int i = 0; i < 4; i++) {
        int row = wc * 64 + i * 16 + m16;
        int ch = (c * 4 + q) ^ (row & 7);
        bf[i] = *(const bf16x8*)(&Ws[row * 64 + ch * 8]);
      }
#pragma unroll
      for (int rt = 0; rt < 2; rt++)
#pragma unroll
        for (int ct = 0; ct < 4; ct++)
          acc[rt][ct] = __builtin_amdgcn_mfma_f32_16x16x32_bf16(af[rt], bf[ct], acc[rt][ct], 0, 0, 0);
    }
    __syncthreads();
  }

  // ---- two-pass epilogue: 32 rows/pass through the 16.9KB buffer ----
  bool all1 = (!pad47) && (col0 + 128 <= S);
  bool all2 = (col0 >= S);
  int row8 = t >> 3, seg = t & 7;  // row8 0..31, seg 0..7
#pragma unroll
  for (int p = 0; p < 2; p++) {
    __syncthreads();  // pass 0: staging reads done; pass 1: pass-0 LDS reads done
    if (wr == p) {
#pragma unroll
      for (int rt = 0; rt < 2; rt++) {
#pragma unroll
        for (int ctt = 0; ctt < 4; ctt++) {
#pragma unroll
          for (int reg = 0; reg < 4; reg++) {
            int rloc = rt * 16 + q * 4 + reg;  // 0..31
            Ls[rloc * 132 + wc * 64 + ctt * 16 + m16] = acc[rt][ctt][reg];
          }
        }
      }
    }
    __syncthreads();
    int grow = row0 + p * 32 + row8;
    if (grow < nrows) {
      const float* lrow = Ls + row8 * 132 + seg * 16;
      int cbase = col0 + seg * 16;
      if (all1) {
        unsigned int q8[4];
#pragma unroll
        for (int kk = 0; kk < 4; kk++)
          q8[kk] = pk4_fp8(lrow[kk * 4], lrow[kk * 4 + 1], lrow[kk * 4 + 2], lrow[kk * 4 + 3]);
        uint4 v8 = {q8[0], q8[1], q8[2], q8[3]};
        *(uint4*)(out8 + (size_t)grow * ld8 + cbase) = v8;
        // fused attention-logit partials: this thread covers 16 ch of head cbase>>6
        float s_p = 0.f, d_p = 0.f;
#pragma unroll
        for (int kk = 0; kk < 16; kk++) {
          s_p += lrow[kk] * a_s[cbase + kk];
          d_p += lrow[kk] * a_d[cbase + kk];
        }
        s_p += __shfl_xor(s_p, 1, 64); s_p += __shfl_xor(s_p, 2, 64);
        d_p += __shfl_xor(d_p, 1, 64); d_p += __shfl_xor(d_p, 2, 64);
        if ((seg & 3) == 0) {
          int head = cbase >> 6;
          alsp[grow * 4 + head] = s_p;
          aldp[grow * 4 + head] = d_p;
        }
      } else if (all2) {
        const float* brow = bias2 + (cbase - S);
        // bf16 skip store (layers 0/1): 16 cols -> 8 packed uints -> 2 uint4 stores
        ushortt* orow = out2b + (size_t)grow * ld2 + (cbase - S);
        unsigned int pk[8];
#pragma unroll
        for (int kk = 0; kk < 8; kk++) {
          unsigned int lo = f2bf(lrow[kk * 2] + brow[kk * 2]);
          unsigned int hi = f2bf(lrow[kk * 2 + 1] + brow[kk * 2 + 1]);
          pk[kk] = lo | (hi << 16);
        }
        uint4 v0 = {pk[0], pk[1], pk[2], pk[3]};
        uint4 v1 = {pk[4], pk[5], pk[6], pk[7]};
        *(uint4*)(orow) = v0;
        *(uint4*)(orow + 8) = v1;
      } else {
        // layer-2 mixed tile: scalar h stores (fp8, padded 47->48) + fp32 skip cols +
        // atomic logit partials (head = c/47, at most 2 heads per thread)
        float pa0 = 0.f, pa1 = 0.f, pd0 = 0.f, pd1 = 0.f;
        int h0 = cbase / 47;
        for (int kk = 0; kk < 16; kk++) {
          int c = cbase + kk;
          if (c >= M) break;
          float v = lrow[kk];
          if (c < S) {
            int hd = c / 47, ch = c - hd * 47;
            int c1 = hd * 48 + ch;
            out8[(size_t)grow * ld8 + c1] =
                (unsigned char)(pk4_fp8(v, 0.f, 0.f, 0.f) & 0xFF);
            if (ch == 46) out8[(size_t)grow * ld8 + c1 + 1] = 0;
            float sw = a_s[hd * 47 + ch], dw = a_d[hd * 47 + ch];
            if (hd == h0) { pa0 += v * sw; pd0 += v * dw; }
            else { pa1 += v * sw; pd1 += v * dw; }
          } else {
            out2f[(size_t)grow * ld2 + (c - S)] = v + bias2[c - S];
          }
        }
        if (pad47 && cbase < S) {
          if (pa0 != 0.f || pd0 != 0.f) {
            atomicAdd(&alsp[grow * 4 + h0], pa0);
            atomicAdd(&aldp[grow * 4 + h0], pd0);
          }
          if ((pa1 != 0.f || pd1 != 0.f) && h0 + 1 < 4) {
            atomicAdd(&alsp[grow * 4 + h0 + 1], pa1);
            atomicAdd(&aldp[grow * 4 + h0 + 1], pd1);
          }
        }
      }
    }
  }
}

// ---------------- fused softmax + aggregate + skip-add + BN-STATS (r24) ---------------
// 4 nodes per block (one per wave, r23). After writing Sb, the block reduces its
// 4 nodes' column sums/sumsq in LDS and atomically adds them into stat copy
// (blockIdx.x & 15) — replaces the separate bn_stats kernel. Stats use the bf16-rounded
// Sb values (identical numerics to the old bn_stats read-back).
__global__ __launch_bounds__(256) void attn_kernel(const unsigned char* __restrict__ H8,
                                                   const float* __restrict__ bias,
                                                   ushortt* __restrict__ Sb,
                                                   float* __restrict__ statp) {
  __shared__ __align__(16) float p_sh[4 * 256];
  __shared__ int s_sh[4 * 64];
  __shared__ float rs_[4 * 256];
  __shared__ float rq_[4 * 256];
  int w = threadIdx.x >> 6, lane = threadIdx.x & 63;
  int n = blockIdx.x * 4 + w;
  float* pw = p_sh + w * 256;
  int* sw_ = s_sh + w * 64;
  int rs = g_rowptr[n], deg = g_rowptr[n + 1] - rs;
  float4 ald = *(const float4*)(g_ald + n * 4);
  int q = lane >> 4;
  float den0 = 0, den1 = 0, den2 = 0, den3 = 0;
  float a0 = 0, a1 = 0, a2 = 0, a3 = 0;
  for (int base = 0; base < deg; base += 64) {
    int j = base + lane;
    float p0 = 0, p1 = 0, p2 = 0, p3 = 0;
    int s = 0;
    if (j < deg) {
      s = g_esrc[rs + j];
      float4 av = *(const float4*)(g_als + s * 4);
      p0 = __expf(lrelu(av.x + ald.x)); den0 += p0;
      p1 = __expf(lrelu(av.y + ald.y)); den1 += p1;
      p2 = __expf(lrelu(av.z + ald.z)); den2 += p2;
      p3 = __expf(lrelu(av.w + ald.w)); den3 += p3;
    }
    pw[lane * 4 + 0] = p0; pw[lane * 4 + 1] = p1;
    pw[lane * 4 + 2] = p2; pw[lane * 4 + 3] = p3;
    sw_[lane] = s;
    int cnt = min(64, deg - base);
    for (int jj = 0; jj < cnt; jj++) {
      int ss = sw_[jj];
      float p = pw[jj * 4 + q];
      unsigned int hv = *(const unsigned int*)(H8 + (size_t)ss * 256 + 4 * lane);
      f32x2 lo = __builtin_amdgcn_cvt_pk_f32_fp8(hv, false);
      f32x2 hi = __builtin_amdgcn_cvt_pk_f32_fp8(hv, true);
      a0 += p * lo.x;
      a1 += p * lo.y;
      a2 += p * hi.x;
      a3 += p * hi.y;
    }
  }
  den0 = wsum(den0); den1 = wsum(den1); den2 = wsum(den2); den3 = wsum(den3);
  float denq = (q == 0) ? den0 : (q == 1) ? den1 : (q == 2) ? den2 : den3;
  float inv = 1.f / (denq + 1e-16f);
  size_t o = (size_t)n * 256 + 4 * lane;
  ushort4 sv = *(const ushort4*)(Sb + o);
  float4 bv = *(const float4*)(bias + 4 * lane);
  ushort4 ov;
  ov.x = f2bf(a0 * inv + bv.x + bf2f(sv.x));
  ov.y = f2bf(a1 * inv + bv.y + bf2f(sv.y));
  ov.z = f2bf(a2 * inv + bv.z + bf2f(sv.z));
  ov.w = f2bf(a3 * inv + bv.w + bf2f(sv.w));
  *(ushort4*)(Sb + o) = ov;
  // ---- fused BN partial stats: block-level column sums over the 4 nodes ----
  float v0 = bf2f(ov.x), v1 = bf2f(ov.y), v2 = bf2f(ov.z), v3 = bf2f(ov.w);
  int cb = w * 256 + 4 * lane;
  rs_[cb + 0] = v0; rs_[cb + 1] = v1; rs_[cb + 2] = v2; rs_[cb + 3] = v3;
  rq_[cb + 0] = v0 * v0; rq_[cb + 1] = v1 * v1; rq_[cb + 2] = v2 * v2; rq_[cb + 3] = v3 * v3;
  __syncthreads();
  int c = threadIdx.x;  // 0..255 = column
  float s = rs_[c] + rs_[256 + c] + rs_[512 + c] + rs_[768 + c];
  float qq = rq_[c] + rq_[256 + c] + rq_[512 + c] + rq_[768 + c];
  int copy = blockIdx.x & (NCOPY - 1);
  atomicAdd(&statp[copy * 512 + c], s);
  atomicAdd(&statp[copy * 512 + 256 + c], qq);
}

// ---------------- layer-2: softmax + aggregate (fp8, ld=192) + mean + skip + log_softmax -
// r23: 4 nodes per block, one per wave, per-wave LDS slices, no barriers.
__global__ __launch_bounds__(256) void attn2_kernel(const unsigned char* __restrict__ H8,
                                                    const float* __restrict__ bias,
                                                    const float* __restrict__ S2,
                                                    float* __restrict__ out) {
  __shared__ __align__(16) float p_sh[4 * 256];
  __shared__ int s_sh[4 * 64];
  __shared__ float xh[4][4][48];
  int w = threadIdx.x >> 6, lane = threadIdx.x & 63;
  int n = blockIdx.x * 4 + w;
  float* pw = p_sh + w * 256;
  int* sw_ = s_sh + w * 64;
  int rs = g_rowptr[n], deg = g_rowptr[n + 1] - rs;
  float4 ald = *(const float4*)(g_ald + n * 4);
  int head = lane / 12;  // valid for lane<48
  float den0 = 0, den1 = 0, den2 = 0, den3 = 0;
  float a0 = 0, a1 = 0, a2 = 0, a3 = 0;
  for (int base = 0; base < deg; base += 64) {
    int j = base + lane;
    float p0 = 0, p1 = 0, p2 = 0, p3 = 0;
    int s = 0;
    if (j < deg) {
      s = g_esrc[rs + j];
      float4 av = *(const float4*)(g_als + s * 4);
      p0 = __expf(lrelu(av.x + ald.x)); den0 += p0;
      p1 = __expf(lrelu(av.y + ald.y)); den1 += p1;
      p2 = __expf(lrelu(av.z + ald.z)); den2 += p2;
      p3 = __expf(lrelu(av.w + ald.w)); den3 += p3;
    }
    pw[lane * 4 + 0] = p0; pw[lane * 4 + 1] = p1;
    pw[lane * 4 + 2] = p2; pw[lane * 4 + 3] = p3;
    sw_[lane] = s;
    int cnt = min(64, deg - base);
    if (lane < 48) {
      for (int jj = 0; jj < cnt; jj++) {
        int ss = sw_[jj];
        float p = pw[jj * 4 + head];
        unsigned int hv = *(const unsigned int*)(H8 + (size_t)ss * 192 + lane * 4);
        f32x2 lo = __builtin_amdgcn_cvt_pk_f32_fp8(hv, false);
        f32x2 hi = __builtin_amdgcn_cvt_pk_f32_fp8(hv, true);
        a0 += p * lo.x;
        a1 += p * lo.y;
        a2 += p * hi.x;
        a3 += p * hi.y;
      }
    }
  }
  den0 = wsum(den0); den1 = wsum(den1); den2 = wsum(den2); den3 = wsum(den3);
  if (lane < 48) {
    float dh = (head == 0) ? den0 : (head == 1) ? den1 : (head == 2) ? den2 : den3;
    float inv = 1.f / (dh + 1e-16f);
    int chin = (lane % 12) * 4;
    xh[w][head][chin + 0] = a0 * inv;
    xh[w][head][chin + 1] = a1 * inv;
    xh[w][head][chin + 2] = a2 * inv;
    xh[w][head][chin + 3] = a3 * inv;
  }
  float v = 0.f;
  if (lane < NCLS)
    v = 0.25f * (xh[w][0][lane] + xh[w][1][lane] + xh[w][2][lane] + xh[w][3][lane]) +
        bias[lane] + S2[(size_t)n * NCLS + lane];
  // fused log_softmax over the 47 classes
  float mv = (lane < NCLS) ? v : -INFINITY;
#pragma unroll
  for (int o = 32; o > 0; o >>= 1) mv = fmaxf(mv, __shfl_xor(mv, o, 64));
  float ex = (lane < NCLS) ? __expf(v - mv) : 0.f;
  float s = wsum(ex);
  if (lane < NCLS) out[(size_t)n * NCLS + lane] = v - mv - logf(s);
}

// ---------------- BatchNorm normalize + ELU (r24: stats reduced in-kernel) -------------
// Reduces the NCOPY stat partials per column (32 loads/thread), folds gamma/beta, then
// processes rows with ushort8 (16B) loads/stores (G13). 480 blocks x 256 threads;
// thread t handles 8-col chunk (t&31) of rows r0 + (t>>5) + 8k. Fb store is swizzled
// (8-col chunks move as units under swz, so 16B stores stay contiguous).
__global__ __launch_bounds__(256) void bn_norm_kernel(const ushortt* __restrict__ Sb,
                                                      const float* __restrict__ gamma,
                                                      const float* __restrict__ beta,
                                                      const float* __restrict__ statp,
                                                      float* __restrict__ zs,
                                                      float* __restrict__ zd) {
  __shared__ float sc_sh[256], off_sh[256];
  int t = threadIdx.x;
  float s = 0.f, qq = 0.f;
#pragma unroll
  for (int k = 0; k < NCOPY; k++) {
    s += statp[k * 512 + t];
    qq += statp[k * 512 + 256 + t];
  }
  float mu = s * (1.f / NN);
  float var = qq * (1.f / NN) - mu * mu;
  float rg = rsqrtf(var + 1e-5f) * gamma[t];
  sc_sh[t] = rg;
  off_sh[t] = beta[t] - mu * rg;
  __syncthreads();
  if (zs) {
    for (int i = blockIdx.x * 256 + t; i < NN * 4; i += gridDim.x * 256) {
      zs[i] = 0.f;
      zd[i] = 0.f;
    }
  }
  int rows = (NN + gridDim.x - 1) / gridDim.x;
  int r0 = blockIdx.x * rows, r1 = min(r0 + rows, NN);
  int chunk = t & 31;  // 8-col chunk
  int ro = t >> 5;     // 0..7
  float scv[8], ofv[8];
#pragma unroll
  for (int k = 0; k < 8; k++) {
    scv[k] = sc_sh[chunk * 8 + k];
    ofv[k] = off_sh[chunk * 8 + k];
  }
  for (int r = r0 + ro; r < r1; r += 8) {
    us8 xv = *(const us8*)(Sb + (size_t)r * 256 + chunk * 8);
    us8 yv;
#pragma unroll
    for (int k = 0; k < 8; k++) {
      float v = bf2f((ushortt)xv[k]) * scv[k] + ofv[k];
      v = v > 0.f ? v : (__expf(v) - 1.f);  // ELU
      yv[k] = f2bf(v);
    }
    int c8 = (chunk & 24) | ((chunk & 7) ^ (r & 7));  // swizzled chunk index
    *(us8*)(g_Fb + ((size_t)r << 8) + c8 * 8) = yv;
  }
}

// ---------------- launch ----------------
extern "C" void kernel_launch(void* const* d_in, const int* in_sizes, int n_in,
                              void* d_out, int out_size, void* d_ws, size_t ws_size,
                              hipStream_t stream) {
  const float* x = (const float*)d_in[0];
  const int* ei = (const int*)d_in[1];
  const int* src = ei;
  const int* dst = ei + EE;
  const float* w0 = (const float*)d_in[2];
  const float* as0 = (const float*)d_in[3];
  const float* ad0 = (const float*)d_in[4];
  const float* b0 = (const float*)d_in[5];
  const float* sw0 = (const float*)d_in[6];
  const float* sb0 = (const float*)d_in[7];
  const float* gm0 = (const float*)d_in[8];
  const float* be0 = (const float*)d_in[9];
  const float* w1 = (const float*)d_in[10];
  const float* as1 = (const float*)d_in[11];
  const float* ad1 = (const float*)d_in[12];
  const float* b1 = (const float*)d_in[13];
  const float* sw1 = (const float*)d_in[14];
  const float* sb1 = (const float*)d_in[15];
  const float* gm1 = (const float*)d_in[16];
  const float* be1 = (const float*)d_in[17];
  const float* w2 = (const float*)d_in[18];
  const float* as2 = (const float*)d_in[19];
  const float* ad2 = (const float*)d_in[20];
  const float* b2 = (const float*)d_in[21];
  const float* sw2 = (const float*)d_in[22];
  const float* sb2 = (const float*)d_in[23];
  float* out = (float*)d_out;

  ushortt *Sb, *Fb, *Xb, *Wc0, *Wc1, *Wc2;
  unsigned char* H8;
  float *S2, *als, *ald, *stat;
  hipGetSymbolAddress((void**)&H8, HIP_SYMBOL(g_H8));
  hipGetSymbolAddress((void**)&Sb, HIP_SYMBOL(g_Sb));
  hipGetSymbolAddress((void**)&S2, HIP_SYMBOL(g_S2));
  hipGetSymbolAddress((void**)&Fb, HIP_SYMBOL(g_Fb));
  hipGetSymbolAddress((void**)&Xb, HIP_SYMBOL(g_Xb));
  hipGetSymbolAddress((void**)&Wc0, HIP_SYMBOL(g_Wc0));
  hipGetSymbolAddress((void**)&Wc1, HIP_SYMBOL(g_Wc1));
  hipGetSymbolAddress((void**)&Wc2, HIP_SYMBOL(g_Wc2));
  hipGetSymbolAddress((void**)&als, HIP_SYMBOL(g_als));
  hipGetSymbolAddress((void**)&ald, HIP_SYMBOL(g_ald));
  hipGetSymbolAddress((void**)&stat, HIP_SYMBOL(g_stat));

  // conversions + zero-init + degree count (one kernel)
  const int convN = CW0 + CW1 + CW2 + NN * 128 + STATZ + EE;
  conv_kernel<<<(convN + 255) / 256, 256, 0, stream>>>(w0, sw0, w1, sw1, w2, sw2, x, dst);

  // CSR: two multi-block scan kernels, then scatter
  scan_a<<<SCAN_B, 256, 0, stream>>>();
  scan_b<<<SCAN_B, 256, 0, stream>>>();
  scatter_kernel<<<(EE + 255) / 256, 256, 0, stream>>>(dst, src);

  const int gy = (NN + 63) / 64;  // 469
  const int ga = NN / 4;          // 7500 (exact)

  // ---- layer 0 ----
  mfma_gemm<<<dim3(4, gy), 256, 0, stream>>>(Xb, Wc0, H8, Sb, nullptr, NN, 128, 512, 256,
                                             256, 256, sb0, 0, as0, ad0, als, ald);
  attn_kernel<<<ga, 256, 0, stream>>>(H8, b0, Sb, stat);
  bn_norm_kernel<<<480, 256, 0, stream>>>(Sb, gm0, be0, stat, nullptr, nullptr);

  // ---- layer 1 ----
  mfma_gemm<<<dim3(4, gy), 256, 0, stream>>>(Fb, Wc1, H8, Sb, nullptr, NN, 256, 512, 256,
                                             256, 256, sb1, 0, as1, ad1, als, ald);
  attn_kernel<<<ga, 256, 0, stream>>>(H8, b1, Sb, stat + NCOPY * 512);
  bn_norm_kernel<<<480, 256, 0, stream>>>(Sb, gm1, be1, stat + NCOPY * 512, als, ald);

  // ---- layer 2 (h fp8 padded: ld=192, 48/head; skip -> S2[N,47] fp32; logits atomic) ----
  mfma_gemm<<<dim3(2, gy), 256, 0, stream>>>(Fb, Wc2, H8, nullptr, S2, NN, 256, 235, 188,
                                             192, 47, sb2, 1, as2, ad2, als, ald);
  attn2_kernel<<<ga, 256, 0, stream>>>(H8, b2, S2, out);
}

// Round 12
// 378.212 us; speedup vs baseline: 1.1795x; 1.0189x over previous
//
#include <hip/hip_runtime.h>
#include <math.h>

#define NN 30000
#define EE 480000
#define FIN 100
#define NCLS 47
#define NCOPY 16   // stat partial copies (contention vs reduce-cost tradeoff)
#define SCAN_B 118 // ceil(30000/256)

typedef unsigned short ushortt;
typedef __attribute__((ext_vector_type(8))) short bf16x8;
typedef __attribute__((ext_vector_type(8))) unsigned short us8;
typedef __attribute__((ext_vector_type(4))) float f32x4;
typedef __attribute__((ext_vector_type(2))) float f32x2;

// ---------------- static device workspace ----------------
// Xb/Fb/Wc* use a bank-conflict-killing swizzle: within each 64-col K-window,
// 8-ushort chunk index is XORed with (row & 7) (r15: conflicts 5.85M -> 682k).
// Logits g_als/g_ald are node-major [n*4+head].
__device__ unsigned char g_H8[(size_t)NN * 256];  // fp8 e4m3 h for the gathers (l2: ld=192)
__device__ ushortt g_Sb[(size_t)NN * 256];   // skip/pre-BN accumulator, bf16 (layers 0/1)
__device__ float   g_S2[(size_t)NN * 48];    // layer-2 skip, fp32 [N,47]
__device__ ushortt g_Fb[(size_t)NN * 256];   // post-BN features bf16, SWIZZLED
__device__ ushortt g_Xb[(size_t)NN * 128];   // x padded 100->128, bf16, SWIZZLED
__device__ ushortt g_Wc0[512 * 128];         // [W0 | SW0]^T bf16, SWIZZLED
__device__ ushortt g_Wc1[512 * 256];         // [W1 | SW1]^T, SWIZZLED
__device__ ushortt g_Wc2[235 * 256];         // [W2(188) | SW2(47)]^T, SWIZZLED
__device__ float g_als[NN * 4];
__device__ float g_ald[NN * 4];
__device__ int   g_rowptr[NN + 1];
__device__ int   g_counts[NN];               // degree counts; zeroed by scan_a each run
__device__ int   g_cur[NN];                  // scatter cursor; zeroed by scan_a each run
__device__ int   g_bsum[128];                // per-chunk totals
__device__ int   g_esrc[EE];                 // src node in CSR (dst-sorted) order
__device__ float g_stat[2 * NCOPY * 512];    // per-layer 16 partial copies of [sum|sumsq]

// ---------------- helpers ----------------
__device__ __forceinline__ float wsum(float v) {
#pragma unroll
  for (int o = 32; o > 0; o >>= 1) v += __shfl_xor(v, o, 64);
  return v;
}
__device__ __forceinline__ float lrelu(float x) { return x > 0.f ? x : 0.2f * x; }
__device__ __forceinline__ ushortt f2bf(float f) {
  unsigned int u = __float_as_uint(f);
  unsigned int r = u + 0x7FFF + ((u >> 16) & 1);
  return (ushortt)(r >> 16);
}
__device__ __forceinline__ float bf2f(ushortt u) {
  return __uint_as_float(((unsigned int)u) << 16);
}
__device__ __forceinline__ unsigned int pk4_fp8(float f0, float f1, float f2, float f3) {
  unsigned int r = 0;
  r = __builtin_amdgcn_cvt_pk_fp8_f32(f0, f1, r, false);
  r = __builtin_amdgcn_cvt_pk_fp8_f32(f2, f3, r, true);
  return r;
}
// swizzled column index: window=64 cols, chunk=8 cols, chunk ^= (row&7)
__device__ __forceinline__ int swz(int row, int k) {
  return (k & ~63) | ((((k >> 3) & 7) ^ (row & 7)) << 3) | (k & 7);
}
// async global->LDS, 16B per lane; lds dest = base + lane*16 (wave-uniform base)
__device__ __forceinline__ void glds16(const ushortt* gp, ushortt* lp) {
  __builtin_amdgcn_global_load_lds(
      (const __attribute__((address_space(1))) unsigned int*)gp,
      (__attribute__((address_space(3))) unsigned int*)lp, 16, 0, 0);
}

// ---------------- conversions + zero-init + degree count (ONE kernel, r24) ------------
// Disjoint index ranges; the count range only touches g_counts, which no other range
// touches (g_counts is zeroed by last run's scan_a / static init on run 1).
#define CW0 (512 * 128)
#define CW1 (512 * 256)
#define CW2 (235 * 256)
#define STATZ (2 * NCOPY * 512)
__global__ void conv_kernel(const float* __restrict__ w0, const float* __restrict__ sw0,
                            const float* __restrict__ w1, const float* __restrict__ sw1,
                            const float* __restrict__ w2, const float* __restrict__ sw2,
                            const float* __restrict__ x, const int* __restrict__ dst) {
  int i = blockIdx.x * blockDim.x + threadIdx.x;
  if (i < CW0) {
    int m = i >> 7, k = i & 127;
    float v = 0.f;
    if (k < FIN) v = (m < 256) ? w0[k * 256 + m] : sw0[k * 256 + (m - 256)];
    g_Wc0[(m << 7) | swz(m, k)] = f2bf(v);
    return;
  }
  i -= CW0;
  if (i < CW1) {
    int m = i >> 8, k = i & 255;
    float v = (m < 256) ? w1[k * 256 + m] : sw1[k * 256 + (m - 256)];
    g_Wc1[(m << 8) | swz(m, k)] = f2bf(v);
    return;
  }
  i -= CW1;
  if (i < CW2) {
    int m = i >> 8, k = i & 255;
    float v = (m < 188) ? w2[(size_t)k * 188 + m] : sw2[(size_t)k * 47 + (m - 188)];
    g_Wc2[(m << 8) | swz(m, k)] = f2bf(v);
    return;
  }
  i -= CW2;
  if (i < NN * 128) {
    int r = i >> 7, k = i & 127;
    g_Xb[(r << 7) | swz(r, k)] = (k < FIN) ? f2bf(x[r * FIN + k]) : 0;
    return;
  }
  i -= NN * 128;
  if (i < STATZ) {
    g_stat[i] = 0.f;
    return;
  }
  i -= STATZ;
  if (i < EE) atomicAdd(&g_counts[dst[i]], 1);
}

// ---------------- CSR scan, TWO multi-block dispatches (r26) --------------------------
__global__ __launch_bounds__(256) void scan_a() {
  __shared__ int sh[256];
  int t = threadIdx.x;
  int i = blockIdx.x * 256 + t;
  int v = (i < NN) ? g_counts[i] : 0;
  sh[t] = v;
  __syncthreads();
  for (int off = 1; off < 256; off <<= 1) {
    int xv = (t >= off) ? sh[t - off] : 0;
    __syncthreads();
    sh[t] += xv;
    __syncthreads();
  }
  if (i < NN) {
    g_rowptr[i] = sh[t] - v;  // local exclusive prefix
    g_counts[i] = 0;
    g_cur[i] = 0;
  }
  if (t == 255) g_bsum[blockIdx.x] = sh[255];
}
__global__ __launch_bounds__(256) void scan_b() {
  __shared__ int sh[4];
  int t = threadIdx.x;
  int b = blockIdx.x;
  int v = (t < b) ? g_bsum[t] : 0;  // b<=117 < 128 entries valid
  float fv = wsum((float)v);        // totals <= 480000, exact in f32
  if ((t & 63) == 0) sh[t >> 6] = (int)fv;
  __syncthreads();
  int off = sh[0] + sh[1] + sh[2] + sh[3];
  int i = b * 256 + t;
  if (i < NN) g_rowptr[i] += off;
  if (i == NN - 1) g_rowptr[NN] = EE;
}
__global__ void scatter_kernel(const int* __restrict__ dst, const int* __restrict__ src) {
  int e = blockIdx.x * blockDim.x + threadIdx.x;
  if (e < EE) {
    int d = dst[e];
    int pos = g_rowptr[d] + atomicAdd(&g_cur[d], 1);
    g_esrc[pos] = src[e];
  }
}

// ---------------- MFMA GEMM, 64x128 tile, BK=64, global_load_lds, swizzled LDS ----------
// r19 structure (best of 4 tried: r18 dbuf, r20 barrier-free, r21 128x128, r22 coop all
// regressed). LDS 24KB: staging 12288 ushorts; epilogue reuses as 32x132 fp32, 2 passes.
__global__ __launch_bounds__(256) void mfma_gemm(
    const ushortt* __restrict__ A, const ushortt* __restrict__ Wt,
    unsigned char* __restrict__ out8, ushortt* __restrict__ out2b,
    float* __restrict__ out2f,
    int nrows, int Kp, int M, int S, int ld8, int ld2,
    const float* __restrict__ bias2, int pad47,
    const float* __restrict__ a_s, const float* __restrict__ a_d,
    float* __restrict__ alsp, float* __restrict__ aldp) {
  __shared__ __align__(16) ushortt smem[12288];
  ushortt* As = smem;            // 64 x 64
  ushortt* Ws = smem + 64 * 64;  // 128 x 64
  float* Ls = (float*)smem;      // 32 x (stride 132) f32
  int t = threadIdx.x;
  int wave = t >> 6, lane = t & 63;
  int row0 = blockIdx.y * 64, col0 = blockIdx.x * 128;
  int wr = wave >> 1, wc = wave & 1;  // 2 row-halves x 2 col-halves
  int m16 = lane & 15, q = lane >> 4;
  int rin8 = lane >> 3;            // 0..7 row within 8-row staging group
  int koff = (lane & 7) * 8;       // k offset in ushorts within 64-k row

  f32x4 acc[2][4];
#pragma unroll
  for (int i = 0; i < 2; i++)
#pragma unroll
    for (int j = 0; j < 4; j++) acc[i][j] = (f32x4){0.f, 0.f, 0.f, 0.f};

  for (int k0 = 0; k0 < Kp; k0 += 64) {
#pragma unroll
    for (int r = 0; r < 2; r++) {
      int lrow = wave * 16 + r * 8;
      int ga = min(row0 + lrow + rin8, nrows - 1);
      glds16(A + (size_t)ga * Kp + k0 + koff, &As[lrow * 64]);
    }
#pragma unroll
    for (int r = 0; r < 4; r++) {
      int lrow = wave * 32 + r * 8;
      int gw = min(col0 + lrow + rin8, M - 1);
      glds16(Wt + (size_t)gw * Kp + k0 + koff, &Ws[lrow * 64]);
    }
    __syncthreads();
#pragma unroll
    for (int c = 0; c < 2; c++) {
      bf16x8 af[2], bf[4];
#pragma unroll
      for (int i = 0; i < 2; i++) {
        int row = wr * 32 + i * 16 + m16;
        int ch = (c * 4 + q) ^ (row & 7);  // de-swizzle: conflict-free across m16 rows
        af[i] = *(const bf16x8*)(&As[row * 64 + ch * 8]);
      }
#pragma unroll
      for (int i = 0; i < 4; i++) {
        int row = wc * 64 + i * 16 + m16;
        int ch = (c * 4 + q) ^ (row & 7);
        bf[i] = *(const bf16x8*)(&Ws[row * 64 + ch * 8]);
      }
#pragma unroll
      for (int rt = 0; rt < 2; rt++)
#pragma unroll
        for (int ct = 0; ct < 4; ct++)
          acc[rt][ct] = __builtin_amdgcn_mfma_f32_16x16x32_bf16(af[rt], bf[ct], acc[rt][ct], 0, 0, 0);
    }
    __syncthreads();
  }

  // ---- two-pass epilogue: 32 rows/pass through the 16.9KB buffer ----
  bool all1 = (!pad47) && (col0 + 128 <= S);
  bool all2 = (col0 >= S);
  int row8 = t >> 3, seg = t & 7;  // row8 0..31, seg 0..7
#pragma unroll
  for (int p = 0; p < 2; p++) {
    __syncthreads();  // pass 0: staging reads done; pass 1: pass-0 LDS reads done
    if (wr == p) {
#pragma unroll
      for (int rt = 0; rt < 2; rt++) {
#pragma unroll
        for (int ctt = 0; ctt < 4; ctt++) {
#pragma unroll
          for (int reg = 0; reg < 4; reg++) {
            int rloc = rt * 16 + q * 4 + reg;  // 0..31
            Ls[rloc * 132 + wc * 64 + ctt * 16 + m16] = acc[rt][ctt][reg];
          }
        }
      }
    }
    __syncthreads();
    int grow = row0 + p * 32 + row8;
    if (grow < nrows) {
      const float* lrow = Ls + row8 * 132 + seg * 16;
      int cbase = col0 + seg * 16;
      if (all1) {
        unsigned int q8[4];
#pragma unroll
        for (int kk = 0; kk < 4; kk++)
          q8[kk] = pk4_fp8(lrow[kk * 4], lrow[kk * 4 + 1], lrow[kk * 4 + 2], lrow[kk * 4 + 3]);
        uint4 v8 = {q8[0], q8[1], q8[2], q8[3]};
        *(uint4*)(out8 + (size_t)grow * ld8 + cbase) = v8;
        // fused attention-logit partials: this thread covers 16 ch of head cbase>>6
        float s_p = 0.f, d_p = 0.f;
#pragma unroll
        for (int kk = 0; kk < 16; kk++) {
          s_p += lrow[kk] * a_s[cbase + kk];
          d_p += lrow[kk] * a_d[cbase + kk];
        }
        s_p += __shfl_xor(s_p, 1, 64); s_p += __shfl_xor(s_p, 2, 64);
        d_p += __shfl_xor(d_p, 1, 64); d_p += __shfl_xor(d_p, 2, 64);
        if ((seg & 3) == 0) {
          int head = cbase >> 6;
          alsp[grow * 4 + head] = s_p;
          aldp[grow * 4 + head] = d_p;
        }
      } else if (all2) {
        const float* brow = bias2 + (cbase - S);
        // bf16 skip store (layers 0/1): 16 cols -> 8 packed uints -> 2 uint4 stores
        ushortt* orow = out2b + (size_t)grow * ld2 + (cbase - S);
        unsigned int pk[8];
#pragma unroll
        for (int kk = 0; kk < 8; kk++) {
          unsigned int lo = f2bf(lrow[kk * 2] + brow[kk * 2]);
          unsigned int hi = f2bf(lrow[kk * 2 + 1] + brow[kk * 2 + 1]);
          pk[kk] = lo | (hi << 16);
        }
        uint4 v0 = {pk[0], pk[1], pk[2], pk[3]};
        uint4 v1 = {pk[4], pk[5], pk[6], pk[7]};
        *(uint4*)(orow) = v0;
        *(uint4*)(orow + 8) = v1;
      } else {
        // layer-2 mixed tile: scalar h stores (fp8, padded 47->48) + fp32 skip cols +
        // atomic logit partials (head = c/47, at most 2 heads per thread)
        float pa0 = 0.f, pa1 = 0.f, pd0 = 0.f, pd1 = 0.f;
        int h0 = cbase / 47;
        for (int kk = 0; kk < 16; kk++) {
          int c = cbase + kk;
          if (c >= M) break;
          float v = lrow[kk];
          if (c < S) {
            int hd = c / 47, ch = c - hd * 47;
            int c1 = hd * 48 + ch;
            out8[(size_t)grow * ld8 + c1] =
                (unsigned char)(pk4_fp8(v, 0.f, 0.f, 0.f) & 0xFF);
            if (ch == 46) out8[(size_t)grow * ld8 + c1 + 1] = 0;
            float sw = a_s[hd * 47 + ch], dw = a_d[hd * 47 + ch];
            if (hd == h0) { pa0 += v * sw; pd0 += v * dw; }
            else { pa1 += v * sw; pd1 += v * dw; }
          } else {
            out2f[(size_t)grow * ld2 + (c - S)] = v + bias2[c - S];
          }
        }
        if (pad47 && cbase < S) {
          if (pa0 != 0.f || pd0 != 0.f) {
            atomicAdd(&alsp[grow * 4 + h0], pa0);
            atomicAdd(&aldp[grow * 4 + h0], pd0);
          }
          if ((pa1 != 0.f || pd1 != 0.f) && h0 + 1 < 4) {
            atomicAdd(&alsp[grow * 4 + h0 + 1], pa1);
            atomicAdd(&aldp[grow * 4 + h0 + 1], pd1);
          }
        }
      }
    }
  }
}

// ---------------- fused softmax + aggregate + skip-add + BN-STATS ---------------------
// r27: 4-wide neighbor-parallel gather. Lane group g=lane>>4 handles neighbor jj+g;
// each lane reads a 16B uint4 chunk (16 channels, chunk m=lane&15) of that neighbor's
// 256B H8 row, accumulating into a[16] (static indexing — no scratch). Inner trip
// count drops 4x (deg -> deg/4). One xor(16)+xor(32) cross-group reduction per node.
// Tail safety: p_sh entries >= deg are exactly 0 (kills garbage-neighbor terms; ss
// defaults to row 0 = finite data, no NaN). Channel coverage: lane writes 4 ch at
// cb2 = m*16 + g*4 (disjoint, complete). BN stats fused as in r24.
__global__ __launch_bounds__(256) void attn_kernel(const unsigned char* __restrict__ H8,
                                                   const float* __restrict__ bias,
                                                   ushortt* __restrict__ Sb,
                                                   float* __restrict__ statp) {
  __shared__ __align__(16) float p_sh[4 * 256];
  __shared__ int s_sh[4 * 64];
  __shared__ float rs_[4 * 256];
  __shared__ float rq_[4 * 256];
  int w = threadIdx.x >> 6, lane = threadIdx.x & 63;
  int n = blockIdx.x * 4 + w;
  float* pw = p_sh + w * 256;
  int* sw_ = s_sh + w * 64;
  int rs = g_rowptr[n], deg = g_rowptr[n + 1] - rs;
  float4 ald = *(const float4*)(g_ald + n * 4);
  int g = lane >> 4;   // neighbor subgroup
  int m = lane & 15;   // 16B chunk within row (16 channels, head m>>2)
  float den0 = 0, den1 = 0, den2 = 0, den3 = 0;
  float a[16];
#pragma unroll
  for (int k = 0; k < 16; k++) a[k] = 0.f;
  for (int base = 0; base < deg; base += 64) {
    int j = base + lane;
    float p0 = 0, p1 = 0, p2 = 0, p3 = 0;
    int s = 0;
    if (j < deg) {
      s = g_esrc[rs + j];
      float4 av = *(const float4*)(g_als + s * 4);
      p0 = __expf(lrelu(av.x + ald.x)); den0 += p0;
      p1 = __expf(lrelu(av.y + ald.y)); den1 += p1;
      p2 = __expf(lrelu(av.z + ald.z)); den2 += p2;
      p3 = __expf(lrelu(av.w + ald.w)); den3 += p3;
    }
    pw[lane * 4 + 0] = p0; pw[lane * 4 + 1] = p1;
    pw[lane * 4 + 2] = p2; pw[lane * 4 + 3] = p3;
    sw_[lane] = s;
    int cnt = min(64, deg - base);
    for (int jj = 0; jj < cnt; jj += 4) {
      int j4 = jj + g;                       // <= 63 (jj <= 60)
      int ss = sw_[j4];
      float p = pw[j4 * 4 + (m >> 2)];       // this chunk's head
      uint4 hv = *(const uint4*)(H8 + (size_t)ss * 256 + m * 16);
      unsigned int hw[4] = {hv.x, hv.y, hv.z, hv.w};
#pragma unroll
      for (int u = 0; u < 4; u++) {
        f32x2 lo = __builtin_amdgcn_cvt_pk_f32_fp8(hw[u], false);
        f32x2 hi = __builtin_amdgcn_cvt_pk_f32_fp8(hw[u], true);
        a[u * 4 + 0] += p * lo.x;
        a[u * 4 + 1] += p * lo.y;
        a[u * 4 + 2] += p * hi.x;
        a[u * 4 + 3] += p * hi.y;
      }
    }
  }
  den0 = wsum(den0); den1 = wsum(den1); den2 = wsum(den2); den3 = wsum(den3);
  // cross-group reduction: sum the 4 neighbor-subgroups' partials
#pragma unroll
  for (int k = 0; k < 16; k++) {
    a[k] += __shfl_xor(a[k], 16, 64);
    a[k] += __shfl_xor(a[k], 32, 64);
  }
  int off = g * 4;
  int cb2 = m * 16 + off;  // this lane's 4 output channels
  int head = m >> 2;
  float denq = (head == 0) ? den0 : (head == 1) ? den1 : (head == 2) ? den2 : den3;
  float inv = 1.f / (denq + 1e-16f);
  size_t o = (size_t)n * 256 + cb2;
  ushort4 sv = *(const ushort4*)(Sb + o);
  float4 bv = *(const float4*)(bias + cb2);
  ushort4 ov;
  ov.x = f2bf(a[off + 0] * inv + bv.x + bf2f(sv.x));
  ov.y = f2bf(a[off + 1] * inv + bv.y + bf2f(sv.y));
  ov.z = f2bf(a[off + 2] * inv + bv.z + bf2f(sv.z));
  ov.w = f2bf(a[off + 3] * inv + bv.w + bf2f(sv.w));
  *(ushort4*)(Sb + o) = ov;
  // ---- fused BN partial stats: block-level column sums over the 4 nodes ----
  float v0 = bf2f(ov.x), v1 = bf2f(ov.y), v2 = bf2f(ov.z), v3 = bf2f(ov.w);
  int cb = w * 256 + cb2;
  rs_[cb + 0] = v0; rs_[cb + 1] = v1; rs_[cb + 2] = v2; rs_[cb + 3] = v3;
  rq_[cb + 0] = v0 * v0; rq_[cb + 1] = v1 * v1; rq_[cb + 2] = v2 * v2; rq_[cb + 3] = v3 * v3;
  __syncthreads();
  int c = threadIdx.x;  // 0..255 = column
  float s = rs_[c] + rs_[256 + c] + rs_[512 + c] + rs_[768 + c];
  float qq = rq_[c] + rq_[256 + c] + rq_[512 + c] + rq_[768 + c];
  int copy = blockIdx.x & (NCOPY - 1);
  atomicAdd(&statp[copy * 512 + c], s);
  atomicAdd(&statp[copy * 512 + 256 + c], qq);
}

// ---------------- layer-2: softmax + aggregate (fp8, ld=192) + mean + skip + log_softmax -
// r27: same 4-wide gather; 192B rows use chunks m<12 (12x16B); m>=12 lanes clamp the
// address (finite data) and carry p=0 so they contribute nothing. Head of chunk m is
// m/3 (16m..16m+15 never crosses a 48-boundary). After xor-reduce, lane (m<12) owns
// channels c192 = m*16 + g*4 .. +3 (within one head; c192%48 <= 44).
__global__ __launch_bounds__(256) void attn2_kernel(const unsigned char* __restrict__ H8,
                                                    const float* __restrict__ bias,
                                                    const float* __restrict__ S2,
                                                    float* __restrict__ out) {
  __shared__ __align__(16) float p_sh[4 * 256];
  __shared__ int s_sh[4 * 64];
  __shared__ float xh[4][4][48];
  int w = threadIdx.x >> 6, lane = threadIdx.x & 63;
  int n = blockIdx.x * 4 + w;
  float* pw = p_sh + w * 256;
  int* sw_ = s_sh + w * 64;
  int rs = g_rowptr[n], deg = g_rowptr[n + 1] - rs;
  float4 ald = *(const float4*)(g_ald + n * 4);
  int g = lane >> 4;
  int m = lane & 15;
  int mc = min(m, 11);       // clamped chunk (m>=12 lanes are dead weight, p=0)
  int headm = mc / 3;        // head of this chunk's channels
  float den0 = 0, den1 = 0, den2 = 0, den3 = 0;
  float a[16];
#pragma unroll
  for (int k = 0; k < 16; k++) a[k] = 0.f;
  for (int base = 0; base < deg; base += 64) {
    int j = base + lane;
    float p0 = 0, p1 = 0, p2 = 0, p3 = 0;
    int s = 0;
    if (j < deg) {
      s = g_esrc[rs + j];
      float4 av = *(const float4*)(g_als + s * 4);
      p0 = __expf(lrelu(av.x + ald.x)); den0 += p0;
      p1 = __expf(lrelu(av.y + ald.y)); den1 += p1;
      p2 = __expf(lrelu(av.z + ald.z)); den2 += p2;
      p3 = __expf(lrelu(av.w + ald.w)); den3 += p3;
    }
    pw[lane * 4 + 0] = p0; pw[lane * 4 + 1] = p1;
    pw[lane * 4 + 2] = p2; pw[lane * 4 + 3] = p3;
    sw_[lane] = s;
    int cnt = min(64, deg - base);
    for (int jj = 0; jj < cnt; jj += 4) {
      int j4 = jj + g;
      int ss = sw_[j4];
      float p = (m < 12) ? pw[j4 * 4 + headm] : 0.f;
      uint4 hv = *(const uint4*)(H8 + (size_t)ss * 192 + mc * 16);
      unsigned int hw[4] = {hv.x, hv.y, hv.z, hv.w};
#pragma unroll
      for (int u = 0; u < 4; u++) {
        f32x2 lo = __builtin_amdgcn_cvt_pk_f32_fp8(hw[u], false);
        f32x2 hi = __builtin_amdgcn_cvt_pk_f32_fp8(hw[u], true);
        a[u * 4 + 0] += p * lo.x;
        a[u * 4 + 1] += p * lo.y;
        a[u * 4 + 2] += p * hi.x;
        a[u * 4 + 3] += p * hi.y;
      }
    }
  }
  den0 = wsum(den0); den1 = wsum(den1); den2 = wsum(den2); den3 = wsum(den3);
#pragma unroll
  for (int k = 0; k < 16; k++) {
    a[k] += __shfl_xor(a[k], 16, 64);
    a[k] += __shfl_xor(a[k], 32, 64);
  }
  if (m < 12) {
    int off = g * 4;
    int c192 = m * 16 + off;      // 4 channels, same head (c192%48 <= 44)
    int hd = c192 / 48;
    int chin = c192 - hd * 48;
    float dh = (hd == 0) ? den0 : (hd == 1) ? den1 : (hd == 2) ? den2 : den3;
    float inv = 1.f / (dh + 1e-16f);
    xh[w][hd][chin + 0] = a[off + 0] * inv;
    xh[w][hd][chin + 1] = a[off + 1] * inv;
    xh[w][hd][chin + 2] = a[off + 2] * inv;
    xh[w][hd][chin + 3] = a[off + 3] * inv;
  }
  float v = 0.f;
  if (lane < NCLS)
    v = 0.25f * (xh[w][0][lane] + xh[w][1][lane] + xh[w][2][lane] + xh[w][3][lane]) +
        bias[lane] + S2[(size_t)n * NCLS + lane];
  // fused log_softmax over the 47 classes
  float mv = (lane < NCLS) ? v : -INFINITY;
#pragma unroll
  for (int o = 32; o > 0; o >>= 1) mv = fmaxf(mv, __shfl_xor(mv, o, 64));
  float ex = (lane < NCLS) ? __expf(v - mv) : 0.f;
  float s = wsum(ex);
  if (lane < NCLS) out[(size_t)n * NCLS + lane] = v - mv - logf(s);
}

// ---------------- BatchNorm normalize + ELU (r24: stats reduced in-kernel) -------------
__global__ __launch_bounds__(256) void bn_norm_kernel(const ushortt* __restrict__ Sb,
                                                      const float* __restrict__ gamma,
                                                      const float* __restrict__ beta,
                                                      const float* __restrict__ statp,
                                                      float* __restrict__ zs,
                                                      float* __restrict__ zd) {
  __shared__ float sc_sh[256], off_sh[256];
  int t = threadIdx.x;
  float s = 0.f, qq = 0.f;
#pragma unroll
  for (int k = 0; k < NCOPY; k++) {
    s += statp[k * 512 + t];
    qq += statp[k * 512 + 256 + t];
  }
  float mu = s * (1.f / NN);
  float var = qq * (1.f / NN) - mu * mu;
  float rg = rsqrtf(var + 1e-5f) * gamma[t];
  sc_sh[t] = rg;
  off_sh[t] = beta[t] - mu * rg;
  __syncthreads();
  if (zs) {
    for (int i = blockIdx.x * 256 + t; i < NN * 4; i += gridDim.x * 256) {
      zs[i] = 0.f;
      zd[i] = 0.f;
    }
  }
  int rows = (NN + gridDim.x - 1) / gridDim.x;
  int r0 = blockIdx.x * rows, r1 = min(r0 + rows, NN);
  int chunk = t & 31;  // 8-col chunk
  int ro = t >> 5;     // 0..7
  float scv[8], ofv[8];
#pragma unroll
  for (int k = 0; k < 8; k++) {
    scv[k] = sc_sh[chunk * 8 + k];
    ofv[k] = off_sh[chunk * 8 + k];
  }
  for (int r = r0 + ro; r < r1; r += 8) {
    us8 xv = *(const us8*)(Sb + (size_t)r * 256 + chunk * 8);
    us8 yv;
#pragma unroll
    for (int k = 0; k < 8; k++) {
      float v = bf2f((ushortt)xv[k]) * scv[k] + ofv[k];
      v = v > 0.f ? v : (__expf(v) - 1.f);  // ELU
      yv[k] = f2bf(v);
    }
    int c8 = (chunk & 24) | ((chunk & 7) ^ (r & 7));  // swizzled chunk index
    *(us8*)(g_Fb + ((size_t)r << 8) + c8 * 8) = yv;
  }
}

// ---------------- launch ----------------
extern "C" void kernel_launch(void* const* d_in, const int* in_sizes, int n_in,
                              void* d_out, int out_size, void* d_ws, size_t ws_size,
                              hipStream_t stream) {
  const float* x = (const float*)d_in[0];
  const int* ei = (const int*)d_in[1];
  const int* src = ei;
  const int* dst = ei + EE;
  const float* w0 = (const float*)d_in[2];
  const float* as0 = (const float*)d_in[3];
  const float* ad0 = (const float*)d_in[4];
  const float* b0 = (const float*)d_in[5];
  const float* sw0 = (const float*)d_in[6];
  const float* sb0 = (const float*)d_in[7];
  const float* gm0 = (const float*)d_in[8];
  const float* be0 = (const float*)d_in[9];
  const float* w1 = (const float*)d_in[10];
  const float* as1 = (const float*)d_in[11];
  const float* ad1 = (const float*)d_in[12];
  const float* b1 = (const float*)d_in[13];
  const float* sw1 = (const float*)d_in[14];
  const float* sb1 = (const float*)d_in[15];
  const float* gm1 = (const float*)d_in[16];
  const float* be1 = (const float*)d_in[17];
  const float* w2 = (const float*)d_in[18];
  const float* as2 = (const float*)d_in[19];
  const float* ad2 = (const float*)d_in[20];
  const float* b2 = (const float*)d_in[21];
  const float* sw2 = (const float*)d_in[22];
  const float* sb2 = (const float*)d_in[23];
  float* out = (float*)d_out;

  ushortt *Sb, *Fb, *Xb, *Wc0, *Wc1, *Wc2;
  unsigned char* H8;
  float *S2, *als, *ald, *stat;
  hipGetSymbolAddress((void**)&H8, HIP_SYMBOL(g_H8));
  hipGetSymbolAddress((void**)&Sb, HIP_SYMBOL(g_Sb));
  hipGetSymbolAddress((void**)&S2, HIP_SYMBOL(g_S2));
  hipGetSymbolAddress((void**)&Fb, HIP_SYMBOL(g_Fb));
  hipGetSymbolAddress((void**)&Xb, HIP_SYMBOL(g_Xb));
  hipGetSymbolAddress((void**)&Wc0, HIP_SYMBOL(g_Wc0));
  hipGetSymbolAddress((void**)&Wc1, HIP_SYMBOL(g_Wc1));
  hipGetSymbolAddress((void**)&Wc2, HIP_SYMBOL(g_Wc2));
  hipGetSymbolAddress((void**)&als, HIP_SYMBOL(g_als));
  hipGetSymbolAddress((void**)&ald, HIP_SYMBOL(g_ald));
  hipGetSymbolAddress((void**)&stat, HIP_SYMBOL(g_stat));

  // conversions + zero-init + degree count (one kernel)
  const int convN = CW0 + CW1 + CW2 + NN * 128 + STATZ + EE;
  conv_kernel<<<(convN + 255) / 256, 256, 0, stream>>>(w0, sw0, w1, sw1, w2, sw2, x, dst);

  // CSR: two multi-block scan kernels, then scatter
  scan_a<<<SCAN_B, 256, 0, stream>>>();
  scan_b<<<SCAN_B, 256, 0, stream>>>();
  scatter_kernel<<<(EE + 255) / 256, 256, 0, stream>>>(dst, src);

  const int gy = (NN + 63) / 64;  // 469
  const int ga = NN / 4;          // 7500 (exact)

  // ---- layer 0 ----
  mfma_gemm<<<dim3(4, gy), 256, 0, stream>>>(Xb, Wc0, H8, Sb, nullptr, NN, 128, 512, 256,
                                             256, 256, sb0, 0, as0, ad0, als, ald);
  attn_kernel<<<ga, 256, 0, stream>>>(H8, b0, Sb, stat);
  bn_norm_kernel<<<480, 256, 0, stream>>>(Sb, gm0, be0, stat, nullptr, nullptr);

  // ---- layer 1 ----
  mfma_gemm<<<dim3(4, gy), 256, 0, stream>>>(Fb, Wc1, H8, Sb, nullptr, NN, 256, 512, 256,
                                             256, 256, sb1, 0, as1, ad1, als, ald);
  attn_kernel<<<ga, 256, 0, stream>>>(H8, b1, Sb, stat + NCOPY * 512);
  bn_norm_kernel<<<480, 256, 0, stream>>>(Sb, gm1, be1, stat + NCOPY * 512, als, ald);

  // ---- layer 2 (h fp8 padded: ld=192, 48/head; skip -> S2[N,47] fp32; logits atomic) ----
  mfma_gemm<<<dim3(2, gy), 256, 0, stream>>>(Fb, Wc2, H8, nullptr, S2, NN, 256, 235, 188,
                                             192, 47, sb2, 1, as2, ad2, als, ald);
  attn2_kernel<<<ga, 256, 0, stream>>>(H8, b2, S2, out);
}